// Round 1
// 162.688 us; speedup vs baseline: 1.0046x; 1.0046x over previous
//
#include <hip/hip_runtime.h>

// Fused grouped-QKV GEMM: out[t,kv,g,d] = sum_e in[t,e]*W[e,kv,g,d] + bias
// M=64, K=4096, N=6144. fp32 in/out.
//
// R8: 2-phase double-buffered LDS pipeline (guide T3-minimum). Stage(s+1) is
// issued before compute(s); counted `s_waitcnt vmcnt(4)` + raw s_barrier
// replaces __syncthreads' vmcnt(0) drain, so the 16KB W-tile DMA for tile s+1
// stays in flight across the barrier and its ~900cy latency hides under
// compute(s). Manual RNE bit-math replaced by (__bf16) casts ->
// v_cvt_pk_bf16_f32 (~10x fewer VALU). W-tile XOR-swizzled via pre-swizzled
// GLDS *source* (LDS dest linear, m104): B-column ds_reads go 4-way -> 2-way
// banks (free). fp32 partials to d_ws + float4 reduce (no atomics).

#define N_COLS 6144
#define K_DIM  4096
#define Q_SZ   (64 * 4096)
#define K_OFF  Q_SZ
#define V_OFF  (Q_SZ + 64 * 1024)
#define OUT_ELEMS 393216   // 64*6144
#define NT     48          // n-tiles of 128
#define KSPLIT 16          // 256 k per block -> 768 blocks (3/CU)
#define BK     32
#define TILES  8           // 256/32

typedef __bf16 bf16x8 __attribute__((ext_vector_type(8)));
typedef float  f32x4  __attribute__((ext_vector_type(4)));

__device__ __forceinline__ int out_index(int t, int n) {
    const int kv = n / 768;
    const int g  = (n >> 7) % 6;
    const int d  = n & 127;
    if (g < 4)  return t * 4096 + kv * 512 + g * 128 + d;   // q
    if (g == 4) return K_OFF + t * 1024 + kv * 128 + d;     // k
    return V_OFF + t * 1024 + kv * 128 + d;                 // v
}

// async global->LDS, 16B per lane (wave-uniform LDS base + lane*16)
#define GLDS(gp, lp) __builtin_amdgcn_global_load_lds(                        \
    (const __attribute__((address_space(1))) void*)(gp),                      \
    (__attribute__((address_space(3))) void*)(lp), 16, 0, 0)

// counted drain: everything except the newest 4 vmem ops (= next-tile GLDS).
#define VWAIT4() asm volatile("s_waitcnt vmcnt(4)" ::: "memory")

__global__ __launch_bounds__(256, 3)
void qkv_gemm(const float* __restrict__ in, const float* __restrict__ w,
              float* __restrict__ part) {
    __shared__ float Ws[2][BK * 128];   // 2 x 16KB fp32 W-tile, [k][n] k-major

    const int tid  = threadIdx.x;
    const int nt   = blockIdx.x % NT;    // adjacent blocks: adjacent n, same k
    const int kq   = blockIdx.x / NT;
    const int n0   = nt * 128;
    const int k0   = kq * (BK * TILES);
    const int wid  = tid >> 6;
    const int lane = tid & 63;
    const int l15  = lane & 15;
    const int kblk = lane >> 4;

    f32x4 acc[2][4];
    #pragma unroll
    for (int a = 0; a < 2; ++a)
        #pragma unroll
        for (int b = 0; b < 4; ++b) acc[a][b] = (f32x4){0.f, 0.f, 0.f, 0.f};

    float4 aloA[4], ahiA[4], aloB[4], ahiB[4];

    // stage W tile: 16KB as 1024 16B slots, slot u -> row k=u>>5, chunk u&31.
    // Source chunk pre-swizzled c' = c ^ ((k>>3)<<2), so LDS word k*128+m
    // holds W[k][m ^ ((k>>3)<<4)]; the read applies the same XOR. kblk pairs
    // {0,2} and {1,3} then share banks 2-way (free) instead of 4-way.
    auto STAGE = [&](int s, int buf) {
        const int kc = k0 + s * BK;
        const float* wr = w + (size_t)kc * N_COLS + n0;
        #pragma unroll
        for (int r = 0; r < 4; ++r) {
            const int u = r * 256 + tid;
            const int c = (u & 31) ^ (((u >> 8) & 3) << 2);
            GLDS(wr + (size_t)(u >> 5) * N_COLS + c * 4, &Ws[buf][u * 4]);
        }
    };

    auto LOADA = [&](int s, float4 (&alo)[4], float4 (&ahi)[4]) {
        const int kc = k0 + s * BK;
        #pragma unroll
        for (int mi = 0; mi < 4; ++mi) {
            const float* ap = in + (size_t)(mi * 16 + l15) * K_DIM + kc + kblk * 8;
            alo[mi] = *(const float4*)ap;
            ahi[mi] = *(const float4*)(ap + 4);
        }
    };

    auto BODY = [&](const float4 (&alo)[4], const float4 (&ahi)[4], int buf) {
        // pack A-frags: element j = k-offset j; (__bf16) cast = HW RNE cvt_pk
        bf16x8 av[4];
        #pragma unroll
        for (int mi = 0; mi < 4; ++mi) {
            av[mi][0] = (__bf16)alo[mi].x; av[mi][1] = (__bf16)alo[mi].y;
            av[mi][2] = (__bf16)alo[mi].z; av[mi][3] = (__bf16)alo[mi].w;
            av[mi][4] = (__bf16)ahi[mi].x; av[mi][5] = (__bf16)ahi[mi].y;
            av[mi][6] = (__bf16)ahi[mi].z; av[mi][7] = (__bf16)ahi[mi].w;
        }
        // wave wid owns n-frags {2*wid, 2*wid+1}
        #pragma unroll
        for (int nfi = 0; nfi < 2; ++nfi) {
            const int nb   = (wid * 2 + nfi) * 16 + l15;
            const int base = kblk * 1024 + (nb ^ (kblk << 4));
            bf16x8 bv;
            #pragma unroll
            for (int j = 0; j < 8; ++j)
                bv[j] = (__bf16)Ws[buf][base + j * 128];
            #pragma unroll
            for (int mi = 0; mi < 4; ++mi)
                acc[nfi][mi] = __builtin_amdgcn_mfma_f32_16x16x32_bf16(
                    av[mi], bv, acc[nfi][mi], 0, 0, 0);
        }
    };

    STAGE(0, 0);
    LOADA(0, aloA, ahiA);

    #pragma unroll
    for (int s = 0; s < TILES; ++s) {
        if (s + 1 < TILES) STAGE(s + 1, (s + 1) & 1);  // issue next-tile DMA
        VWAIT4();                                       // drain stage(s)+A(s)
        __builtin_amdgcn_s_barrier();                   // Ws[s&1] valid
        if ((s & 1) == 0) {
            if (s + 1 < TILES) LOADA(s + 1, aloB, ahiB);
            BODY(aloA, ahiA, 0);
        } else {
            if (s + 1 < TILES) LOADA(s + 1, aloA, ahiA);
            BODY(aloB, ahiB, 1);
        }
        __builtin_amdgcn_s_barrier();                   // reads done before overwrite
    }

    // partials: C/D col = l15 (n), row = kblk*4 + r (token within m-frag)
    float* pb = part + (size_t)kq * OUT_ELEMS;
    #pragma unroll
    for (int nfi = 0; nfi < 2; ++nfi) {
        const int n = n0 + (wid * 2 + nfi) * 16 + l15;
        #pragma unroll
        for (int mi = 0; mi < 4; ++mi) {
            #pragma unroll
            for (int r = 0; r < 4; ++r) {
                const int t = mi * 16 + kblk * 4 + r;
                pb[(size_t)t * N_COLS + n] = acc[nfi][mi][r];
            }
        }
    }
}

// sum KSPLIT partials + bias, scatter to q|k|v. float4 lanes: d-chunks are
// 4-aligned and never cross a 128-d block, so out_index(t,n)..+3 contiguous.
__global__ __launch_bounds__(256)
void qkv_reduce(const float* __restrict__ part, const float* __restrict__ bias,
                float* __restrict__ out) {
    const int i = (blockIdx.x * 256 + threadIdx.x) << 2;   // 0..393212, 4-stride
    const int t = i / N_COLS;
    const int n = i - t * N_COLS;
    f32x4 s = *(const f32x4*)(bias + n);
    #pragma unroll
    for (int kq = 0; kq < KSPLIT; ++kq)
        s += *(const f32x4*)(part + (size_t)kq * OUT_ELEMS + i);
    *(f32x4*)(out + out_index(t, n)) = s;
}

extern "C" void kernel_launch(void* const* d_in, const int* in_sizes, int n_in,
                              void* d_out, int out_size, void* d_ws, size_t ws_size,
                              hipStream_t stream) {
    const float* in   = (const float*)d_in[0];  // [64, 4096]
    const float* w    = (const float*)d_in[1];  // [4096, 8, 6, 128]
    const float* bias = (const float*)d_in[2];  // [8, 6, 128]
    float* out  = (float*)d_out;
    float* part = (float*)d_ws;                 // 16 * 1.57MB = 25.2MB fp32

    qkv_gemm<<<NT * KSPLIT, 256, 0, stream>>>(in, w, part);
    qkv_reduce<<<OUT_ELEMS / 1024, 256, 0, stream>>>(part, bias, out);
}